// Round 1
// baseline (793.553 us; speedup 1.0000x reference)
//
#include <hip/hip_runtime.h>
#include <stdint.h>

typedef __attribute__((ext_vector_type(4))) float f32x4;
typedef __attribute__((ext_vector_type(8))) __bf16 bf16x8;

#define NB 2
#define NS 2048
#define ND 2048
#define NH 16
#define NHD 128
#define NM (NB*NS)      // 4096 rows
#define NQKV (3*ND)     // 6144

__device__ __forceinline__ short f2bf(float f) {
  union { float f; uint32_t u; } c; c.f = f;
  uint32_t r = (c.u + 0x7FFFu + ((c.u >> 16) & 1u)) >> 16;
  return (short)r;
}

__device__ __forceinline__ void gl_lds16(const short* g, short* l) {
  __builtin_amdgcn_global_load_lds(
      (const __attribute__((address_space(1))) void*)g,
      (__attribute__((address_space(3))) void*)l, 16, 0, 0);
}

// ---------------- fp32 -> bf16 elementwise ----------------
__global__ __launch_bounds__(256) void cvt_bf16_kernel(const float* __restrict__ in,
                                                       short* __restrict__ out, int n4) {
  int i = blockIdx.x * 256 + threadIdx.x;
  if (i >= n4) return;
  float4 v = ((const float4*)in)[i];
  short4 o;
  o.x = f2bf(v.x); o.y = f2bf(v.y); o.z = f2bf(v.z); o.w = f2bf(v.w);
  ((short4*)out)[i] = o;
}

// ---------------- fp32 [rows][cols] -> bf16 [cols][rows] ----------------
__global__ __launch_bounds__(256) void transpose_cvt_kernel(const float* __restrict__ in,
                                                            short* __restrict__ out,
                                                            int rows, int cols) {
  __shared__ float tile[64][65];
  const int tx = threadIdx.x, ty = threadIdx.y;
  const int r0 = blockIdx.y * 64, c0 = blockIdx.x * 64;
  for (int i = ty; i < 64; i += 4)
    tile[i][tx] = in[(size_t)(r0 + i) * cols + c0 + tx];
  __syncthreads();
  for (int i = ty; i < 64; i += 4)
    out[(size_t)(c0 + i) * rows + r0 + tx] = f2bf(tile[tx][i]);
}

// ---------------- bf16 GEMM: C = A[M][K] * Bt[N][K]^T, 128x128 tile ----------------
// EPI 0: QKV epilogue -> scatter to Q (scaled), K, Vt per-head buffers (+bias)
// EPI 1: out epilogue -> fp32 out = acc + bias[col] + residual[row*N+col]
template<int EPI>
__global__ __launch_bounds__(256) void gemm_kernel(
    const short* __restrict__ A, const short* __restrict__ Bt, int K, int N,
    const float* __restrict__ bias,
    short* __restrict__ Qb, short* __restrict__ Kb, short* __restrict__ Vtb,
    const float* __restrict__ residual, float* __restrict__ out) {
  const int tid = threadIdx.x;
  const int w = tid >> 6, l = tid & 63;
  const int l15 = l & 15, l4 = l >> 4;
  const int wm = (w >> 1) * 64, wn = (w & 1) * 64;
  const int rowBase = blockIdx.y * 128, colBase = blockIdx.x * 128;

  __shared__ short As[2][128 * 32];
  __shared__ short Bs[2][128 * 32];

  f32x4 acc[4][4] = {};

  const int sRow = tid >> 2;          // 0..63
  const int sCol = (tid & 3) * 8;
  const short* gA0 = A + (size_t)(rowBase + sRow) * K + sCol;
  const short* gB0 = Bt + (size_t)(colBase + sRow) * K + sCol;
  const int ldsW = w * 512;           // shorts

  const int nk = K / 32;

#define STAGE(buf, k0) do {                                      \
    gl_lds16(gA0 + (k0),                 &As[buf][ldsW]);        \
    gl_lds16(gA0 + (size_t)64*K + (k0),  &As[buf][2048 + ldsW]); \
    gl_lds16(gB0 + (k0),                 &Bs[buf][ldsW]);        \
    gl_lds16(gB0 + (size_t)64*K + (k0),  &Bs[buf][2048 + ldsW]); \
  } while (0)

  STAGE(0, 0);
  __syncthreads();
  int cur = 0;
  for (int kt = 0; kt < nk; ++kt) {
    if (kt + 1 < nk) STAGE(cur ^ 1, (kt + 1) * 32);
    bf16x8 a[4], b[4];
#pragma unroll
    for (int i = 0; i < 4; ++i) {
      a[i] = *(const bf16x8*)&As[cur][(wm + i * 16 + l15) * 32 + l4 * 8];
      b[i] = *(const bf16x8*)&Bs[cur][(wn + i * 16 + l15) * 32 + l4 * 8];
    }
#pragma unroll
    for (int i = 0; i < 4; ++i)
#pragma unroll
      for (int j = 0; j < 4; ++j)
        acc[i][j] = __builtin_amdgcn_mfma_f32_16x16x32_bf16(a[i], b[j], acc[i][j], 0, 0, 0);
    __syncthreads();
    cur ^= 1;
  }
#undef STAGE

#pragma unroll
  for (int i = 0; i < 4; ++i) {
#pragma unroll
    for (int j = 0; j < 4; ++j) {
#pragma unroll
      for (int r = 0; r < 4; ++r) {
        const int row = rowBase + wm + i * 16 + l4 * 4 + r;
        const int col = colBase + wn + j * 16 + l15;
        float v = acc[i][j][r] + bias[col];
        if (EPI == 0) {
          // col in [0,6144): h = col/384, sub = col%384; type = sub>>7, hd = sub&127
          const int h = col / 384;
          const int sub = col - h * 384;
          const int t = sub >> 7, hd = sub & 127;
          const int bb = row >> 11, s = row & 2047;
          const size_t bh = (size_t)bb * NH + h;
          if (t == 0)      Qb[(bh * NS + s) * NHD + hd] = f2bf(v * 0.08838834764831845f);
          else if (t == 1) Kb[(bh * NS + s) * NHD + hd] = f2bf(v);
          else             Vtb[(bh * NHD + hd) * NS + s] = f2bf(v);
        } else {
          const size_t idx = (size_t)row * N + col;
          out[idx] = v + residual[idx];
        }
      }
    }
  }
}

// ---------------- flash attention ----------------
// grid: (S/64, B*H); 4 waves/block, each wave owns 16 q-rows.
__global__ __launch_bounds__(256) void attn_kernel(
    const short* __restrict__ Qb, const short* __restrict__ Kb,
    const short* __restrict__ Vtb, const float* __restrict__ alibi,
    const int* __restrict__ amask, short* __restrict__ Ob) {
  const int tid = threadIdx.x;
  const int w = tid >> 6, l = tid & 63;
  const int l15 = l & 15, l4 = l >> 4;
  const int bh = blockIdx.y;
  const int bb = bh >> 4, h = bh & 15;
  const int q0 = blockIdx.x * 64;
  const int qw = q0 + w * 16;

  __shared__ short Plds[4][16 * 32];

  // Q fragments: row = qw + l15, k-slices over HD=128
  const short* qptr = Qb + ((size_t)bh * NS + qw + l15) * NHD + l4 * 8;
  bf16x8 qf[4];
#pragma unroll
  for (int s = 0; s < 4; ++s) qf[s] = *(const bf16x8*)(qptr + s * 32);

  f32x4 acc[8] = {};
  float mrow[4], lrow[4];
#pragma unroll
  for (int r = 0; r < 4; ++r) { mrow[r] = -1e30f; lrow[r] = 0.f; }

  const int nkt = (q0 + 64) / 32;  // causal: keys < q0+64
  const short* kbase = Kb + (size_t)bh * NS * NHD;
  const short* vbase = Vtb + (size_t)bh * NHD * NS;
  const float* abase = alibi + (size_t)bh * NS;
  const int* mbase = amask + bb * NS;

  for (int kt = 0; kt < nkt; ++kt) {
    const int k0 = kt * 32;
    f32x4 s0 = {}, s1 = {};
    const short* kp0 = kbase + (size_t)(k0 + l15) * NHD + l4 * 8;
    const short* kp1 = kp0 + 16 * NHD;
#pragma unroll
    for (int s = 0; s < 4; ++s) {
      bf16x8 kf0 = *(const bf16x8*)(kp0 + s * 32);
      bf16x8 kf1 = *(const bf16x8*)(kp1 + s * 32);
      s0 = __builtin_amdgcn_mfma_f32_16x16x32_bf16(qf[s], kf0, s0, 0, 0, 0);
      s1 = __builtin_amdgcn_mfma_f32_16x16x32_bf16(qf[s], kf1, s1, 0, 0, 0);
    }
    const float al0 = abase[k0 + l15];
    const float al1 = abase[k0 + 16 + l15];
    const bool ok0 = mbase[k0 + l15] != 0;
    const bool ok1 = mbase[k0 + 16 + l15] != 0;
    const int kg0 = k0 + l15, kg1 = kg0 + 16;

    float p0[4], p1[4], tmax[4];
#pragma unroll
    for (int r = 0; r < 4; ++r) {
      const int qrow = qw + l4 * 4 + r;
      float v0 = (ok0 && kg0 <= qrow) ? (s0[r] + al0) : -1e30f;
      float v1 = (ok1 && kg1 <= qrow) ? (s1[r] + al1) : -1e30f;
      p0[r] = v0; p1[r] = v1;
      tmax[r] = fmaxf(v0, v1);
    }
#pragma unroll
    for (int r = 0; r < 4; ++r) {
#pragma unroll
      for (int off = 1; off < 16; off <<= 1)
        tmax[r] = fmaxf(tmax[r], __shfl_xor(tmax[r], off, 64));
    }
    float alpha[4];
#pragma unroll
    for (int r = 0; r < 4; ++r) {
      const float mnew = fmaxf(mrow[r], tmax[r]);
      alpha[r] = __expf(mrow[r] - mnew);
      mrow[r] = mnew;
      const float e0 = __expf(p0[r] - mnew);
      const float e1 = __expf(p1[r] - mnew);
      p0[r] = e0; p1[r] = e1;
      float ps = e0 + e1;
#pragma unroll
      for (int off = 1; off < 16; off <<= 1)
        ps += __shfl_xor(ps, off, 64);
      lrow[r] = lrow[r] * alpha[r] + ps;
    }
#pragma unroll
    for (int t = 0; t < 8; ++t)
#pragma unroll
      for (int r = 0; r < 4; ++r)
        acc[t][r] *= alpha[r];

    // P -> LDS (re-layout C-frag -> A-frag), bf16
#pragma unroll
    for (int r = 0; r < 4; ++r) {
      Plds[w][(l4 * 4 + r) * 32 + l15] = f2bf(p0[r]);
      Plds[w][(l4 * 4 + r) * 32 + 16 + l15] = f2bf(p1[r]);
    }
    asm volatile("s_waitcnt lgkmcnt(0)" ::: "memory");
    const bf16x8 pa = *(const bf16x8*)&Plds[w][l15 * 32 + l4 * 8];
    const short* vp = vbase + (size_t)l15 * NS + k0 + l4 * 8;
#pragma unroll
    for (int t = 0; t < 8; ++t) {
      bf16x8 vf = *(const bf16x8*)(vp + (size_t)t * 16 * NS);
      acc[t] = __builtin_amdgcn_mfma_f32_16x16x32_bf16(pa, vf, acc[t], 0, 0, 0);
    }
  }

  float inv[4];
#pragma unroll
  for (int r = 0; r < 4; ++r) inv[r] = 1.0f / lrow[r];
  short* obase = Ob + ((size_t)bb * NS + qw) * ND + h * NHD;
#pragma unroll
  for (int t = 0; t < 8; ++t)
#pragma unroll
    for (int r = 0; r < 4; ++r)
      obase[(size_t)(l4 * 4 + r) * ND + t * 16 + l15] = f2bf(acc[t][r] * inv[r]);
}

extern "C" void kernel_launch(void* const* d_in, const int* in_sizes, int n_in,
                              void* d_out, int out_size, void* d_ws, size_t ws_size,
                              hipStream_t stream) {
  const float* hidden   = (const float*)d_in[0];
  const float* residual = (const float*)d_in[1];
  const float* alibi    = (const float*)d_in[2];
  const float* W_qkv    = (const float*)d_in[3];
  const float* b_qkv    = (const float*)d_in[4];
  const float* W_o      = (const float*)d_in[5];
  const float* b_o      = (const float*)d_in[6];
  const int*   amask    = (const int*)d_in[7];
  float* out = (float*)d_out;

  char* p = (char*)d_ws;
  short* Abuf  = (short*)p; p += (size_t)NM * ND * 2;      // 16 MB hidden bf16
  short* WqkvT = (short*)p; p += (size_t)NQKV * ND * 2;    // 24 MB W_qkv^T bf16
  short* WoT   = (short*)p; p += (size_t)ND * ND * 2;      //  8 MB W_o^T bf16
  short* Qb    = (short*)p; p += (size_t)NB * NH * NS * NHD * 2;  // 16 MB
  short* Kb    = (short*)p; p += (size_t)NB * NH * NS * NHD * 2;  // 16 MB
  short* Vtb   = (short*)p; p += (size_t)NB * NH * NS * NHD * 2;  // 16 MB
  short* Ob    = (short*)p; p += (size_t)NM * ND * 2;      // 16 MB

  cvt_bf16_kernel<<<(NM * ND / 4) / 256, 256, 0, stream>>>(hidden, Abuf, NM * ND / 4);
  transpose_cvt_kernel<<<dim3(NQKV / 64, ND / 64), dim3(64, 4), 0, stream>>>(W_qkv, WqkvT, ND, NQKV);
  transpose_cvt_kernel<<<dim3(ND / 64, ND / 64), dim3(64, 4), 0, stream>>>(W_o, WoT, ND, ND);
  gemm_kernel<0><<<dim3(NQKV / 128, NM / 128), 256, 0, stream>>>(
      Abuf, WqkvT, ND, NQKV, b_qkv, Qb, Kb, Vtb, nullptr, nullptr);
  attn_kernel<<<dim3(NS / 64, NB * NH), 256, 0, stream>>>(Qb, Kb, Vtb, alibi, amask, Ob);
  gemm_kernel<1><<<dim3(ND / 128, NM / 128), 256, 0, stream>>>(
      Ob, WoT, ND, ND, b_o, nullptr, nullptr, nullptr, residual, out);
}